// Round 16
// baseline (53.946 us; speedup 1.0000x reference)
//
#include <hip/hip_runtime.h>

#define B_   4
#define LQ_  256
#define LK_  512
#define DIN_ 512
#define H_   256
#define DV_  512

#define L2E 1.4426950408889634f   // log2(e)
// tanh(x) = 1 - 2/(e^{2x}+1);  e^{2(q+k)} = e^{2q} * e^{2k}.
// eq2 = 2^clamp(2q*L2E,±126), ek2 likewise: each finite & nonzero.
// product inf -> rcp 0 (tanh=+1 exact); product 0 -> rcp 1 (tanh=-1 exact).

// =====================================================================
// Kernel 1: proj PARTIAL GEMM, 32-row x 128-h tiles (occupancy fix).
// 256 thr, micro 4r x 4h. d-split: Q=4 (128d), K=8 (64d).
// grid = Q:256 + K:1024 = 1280 blocks (~768 live = 3/CU; LDS 42.5 KB).
//  Q out: qpart[ds4][(b,i)][h]   row-major
//  K out: ekTpart[ds8][b][h][j]  transposed
// =====================================================================
__global__ __launch_bounds__(256) void proj_partial_kernel(
    const float* __restrict__ Q, const float* __restrict__ K,
    const float* __restrict__ Wq, const float* __restrict__ Wk,
    const int* __restrict__ valid_lens,
    float* __restrict__ qpart, float* __restrict__ ekTpart) {
  __shared__ float xs[32][68];     //  8.7 KB
  __shared__ float ws[64][132];    // 33.8 KB

  const int blk = blockIdx.x;
  const bool isQ = blk < 256;
  int b, row0, h0, ds, dspan;
  if (isQ) {
    ds = blk & 3; h0 = ((blk >> 2) & 1) * 128;
    const int rt = blk >> 3;            // 0..31
    b = rt >> 3; row0 = (rt & 7) * 32;
    dspan = 128;
  } else {
    const int u = blk - 256;            // 0..1023
    ds = u & 7; h0 = ((u >> 3) & 1) * 128;
    const int rt = u >> 4;              // 0..63, batch-interleaved
    b = rt & 3; row0 = (rt >> 2) * 32;
    if (row0 >= valid_lens[b]) return;  // dead K tile (uniform, before barriers)
    dspan = 64;
  }
  const int L = isQ ? LQ_ : LK_;
  const float* __restrict__ X  = (isQ ? Q : K) + ((size_t)(b * L + row0)) * DIN_ + ds * dspan;
  const float* __restrict__ Wb = (isQ ? Wq : Wk) + (size_t)(ds * dspan) * H_ + h0;

  const int t = threadIdx.x;
  const int hthr = t & 31;    // h = h0 + 4*hthr
  const int rthr = t >> 5;    // rows row0 + rthr*4 .. +3

  float acc[4][4];
#pragma unroll
  for (int r = 0; r < 4; ++r)
#pragma unroll
    for (int c = 0; c < 4; ++c) acc[r][c] = 0.f;

  for (int dd = 0; dd < dspan; dd += 64) {
    __syncthreads();
    // stage X: 32 rows x 64 d = 512 f4 / 256 thr = 2 each
#pragma unroll
    for (int u = 0; u < 2; ++u) {
      const int f = t + 256 * u;
      const int r = f >> 4, c4 = (f & 15) << 2;
      *(float4*)&xs[r][c4] = *(const float4*)&X[(size_t)r * DIN_ + dd + c4];
    }
    // stage W: 64 d x 128 h = 2048 f4 / 256 thr = 8 each
#pragma unroll
    for (int u = 0; u < 8; ++u) {
      const int f = t + 256 * u;
      const int k = f >> 5, c4 = (f & 31) << 2;
      *(float4*)&ws[k][c4] = *(const float4*)&Wb[(size_t)(dd + k) * H_ + c4];
    }
    __syncthreads();

    for (int k = 0; k < 64; k += 8) {
      float4 w4[8];
#pragma unroll
      for (int k8 = 0; k8 < 8; ++k8)
        w4[k8] = *(const float4*)&ws[k + k8][4 * hthr];
#pragma unroll
      for (int rr = 0; rr < 4; ++rr) {
        const float4 xa = *(const float4*)&xs[rthr * 4 + rr][k];
        const float4 xb = *(const float4*)&xs[rthr * 4 + rr][k + 4];
        const float xv[8] = {xa.x, xa.y, xa.z, xa.w, xb.x, xb.y, xb.z, xb.w};
#pragma unroll
        for (int k8 = 0; k8 < 8; ++k8) {
          acc[rr][0] = fmaf(xv[k8], w4[k8].x, acc[rr][0]);
          acc[rr][1] = fmaf(xv[k8], w4[k8].y, acc[rr][1]);
          acc[rr][2] = fmaf(xv[k8], w4[k8].z, acc[rr][2]);
          acc[rr][3] = fmaf(xv[k8], w4[k8].w, acc[rr][3]);
        }
      }
    }
  }

  if (isQ) {
    float* dst = qpart + (size_t)ds * (B_ * LQ_ * H_);
#pragma unroll
    for (int rr = 0; rr < 4; ++rr) {
      const int row = row0 + rthr * 4 + rr;
      float4 o = {acc[rr][0], acc[rr][1], acc[rr][2], acc[rr][3]};
      *(float4*)&dst[(size_t)(b * LQ_ + row) * H_ + h0 + 4 * hthr] = o;
    }
  } else {
    float* dst = ekTpart + (size_t)ds * (B_ * H_ * LK_);
#pragma unroll
    for (int c = 0; c < 4; ++c) {
      const int h = h0 + 4 * hthr + c;
      float4 o = {acc[0][c], acc[1][c], acc[2][c], acc[3][c]};
      *(float4*)&dst[((size_t)b * H_ + h) * LK_ + row0 + rthr * 4] = o;
    }
  }
}

// =====================================================================
// Kernel 2: combine 8 ekT partials + SQUARED exp: ek2 = 2^clamp(2k*L2E,±126)
// =====================================================================
__global__ __launch_bounds__(512) void combine_ek_kernel(
    const float* __restrict__ ekTpart, float* __restrict__ ek2) {
  const int k4 = blockIdx.x * 512 + threadIdx.x;
  const size_t KN4 = (size_t)B_ * H_ * LK_ / 4;
  const float4* src = (const float4*)ekTpart;
  float4 s = src[k4];
#pragma unroll
  for (int p = 1; p < 8; ++p) {
    const float4 v = src[p * KN4 + k4];
    s.x += v.x; s.y += v.y; s.z += v.z; s.w += v.w;
  }
  float4 o;
  o.x = exp2f(fminf(fmaxf(s.x * (2.f * L2E), -126.f), 126.f));
  o.y = exp2f(fminf(fmaxf(s.y * (2.f * L2E), -126.f), 126.f));
  o.z = exp2f(fminf(fmaxf(s.z * (2.f * L2E), -126.f), 126.f));
  o.w = exp2f(fminf(fmaxf(s.w * (2.f * L2E), -126.f), 126.f));
  ((float4*)ek2)[k4] = o;
}

// =====================================================================
// Kernel 3: FUSED eq-combine + scores + masked softmax + AV.
// block = (b, 2 q-rows), 512 thr = 512 j, grid 512 (2/CU), batch-pair
// swizzle. Phase 1 h-unroll 16 -> 16 kv loads in flight.
// Inner: fmaf(q2,k2,1) -> rcp -> fmaf  (2 VALU + 1 trans / element).
// =====================================================================
__global__ __launch_bounds__(512) void fused_attn_kernel(
    const float* __restrict__ qpart, const float* __restrict__ ek2,
    const float* __restrict__ wv, const int* __restrict__ valid_lens,
    const float* __restrict__ V, float* __restrict__ out) {
  __shared__ float eqs[2][260];
  __shared__ float wvs[256];
  __shared__ float2 p2s[LK_];
  __shared__ float redm[8][2], reds[8][2];
  __shared__ float wsum_s;

  const int blk = blockIdx.x;
  const int b  = (blk & 3) ^ ((blk >> 8) & 1);
  const int i0 = (blk >> 2) * 2;
  const int vl = valid_lens[b];
  const int t = threadIdx.x;
  const int lane = t & 63, wave = t >> 6;

  // ---- phase 0: eq2 rows (squared exp), wv stage, wsum ----
  const size_t QN = (size_t)B_ * LQ_ * H_;
  {
    const int i = t >> 8, h = t & 255;
    const size_t base = (size_t)(b * LQ_ + i0 + i) * H_ + h;
    const float v = qpart[base] + qpart[QN + base] +
                    qpart[2 * QN + base] + qpart[3 * QN + base];
    eqs[i][h] = exp2f(fminf(fmaxf(v * (2.f * L2E), -126.f), 126.f));
  }
  if (t < 256) wvs[t] = wv[t];
  if (t < 64) {
    float s = wv[t] + wv[t + 64] + wv[t + 128] + wv[t + 192];
#pragma unroll
    for (int off = 32; off; off >>= 1) s += __shfl_xor(s, off);
    if (t == 0) wsum_s = s;
  }
  __syncthreads();
  const float Wsum = wsum_s;

  // ---- phase 1: scores for j = t (2 rows), 16 loads in flight ----
  const bool valid = t < vl;
  float s[2] = {-3.0e38f, -3.0e38f};
  if (valid) {
    const float* __restrict__ kb = ek2 + (size_t)b * H_ * LK_ + t;
    float a0 = 0.f, a1 = 0.f;
    for (int h = 0; h < H_; h += 16) {
      float kv[16];
#pragma unroll
      for (int u = 0; u < 16; ++u)
        kv[u] = kb[(size_t)(h + u) * LK_];          // 16 coalesced loads in flight
#pragma unroll
      for (int g = 0; g < 4; ++g) {
        const float4 w4  = *(const float4*)&wvs[h + 4 * g];
        const float4 q0v = *(const float4*)&eqs[0][h + 4 * g];
        const float4 q1v = *(const float4*)&eqs[1][h + 4 * g];
        const float ww[4] = {w4.x, w4.y, w4.z, w4.w};
        const float q0[4] = {q0v.x, q0v.y, q0v.z, q0v.w};
        const float q1[4] = {q1v.x, q1v.y, q1v.z, q1v.w};
#pragma unroll
        for (int u = 0; u < 4; ++u) {
          const float k2 = kv[4 * g + u];
          a0 = fmaf(ww[u], __builtin_amdgcn_rcpf(fmaf(q0[u], k2, 1.f)), a0);
          a1 = fmaf(ww[u], __builtin_amdgcn_rcpf(fmaf(q1[u], k2, 1.f)), a1);
        }
      }
    }
    s[0] = fmaf(-2.f, a0, Wsum);
    s[1] = fmaf(-2.f, a1, Wsum);
  }

  // ---- phase 2: masked softmax over j ----
  float m[2] = {s[0], s[1]};
#pragma unroll
  for (int off = 32; off; off >>= 1)
#pragma unroll
    for (int i = 0; i < 2; ++i) m[i] = fmaxf(m[i], __shfl_xor(m[i], off));
  if (lane == 0)
#pragma unroll
    for (int i = 0; i < 2; ++i) redm[wave][i] = m[i];
  __syncthreads();
  float e[2], sum[2];
#pragma unroll
  for (int i = 0; i < 2; ++i) {
    float mx = redm[0][i];
#pragma unroll
    for (int w = 1; w < 8; ++w) mx = fmaxf(mx, redm[w][i]);
    e[i] = valid ? __expf(s[i] - mx) : 0.f;
    sum[i] = e[i];
  }
#pragma unroll
  for (int off = 32; off; off >>= 1)
#pragma unroll
    for (int i = 0; i < 2; ++i) sum[i] += __shfl_xor(sum[i], off);
  if (lane == 0)
#pragma unroll
    for (int i = 0; i < 2; ++i) reds[wave][i] = sum[i];
  __syncthreads();
  {
    float tot[2];
#pragma unroll
    for (int i = 0; i < 2; ++i) {
      tot[i] = reds[0][i];
#pragma unroll
      for (int w = 1; w < 8; ++w) tot[i] += reds[w][i];
    }
    float2 pv;
    pv.x = e[0] * __builtin_amdgcn_rcpf(tot[0]);
    pv.y = e[1] * __builtin_amdgcn_rcpf(tot[1]);
    p2s[t] = pv;
  }
  __syncthreads();

  // ---- phase 3: AV (thread = v-column), x8-unrolled V loads ----
  const float* __restrict__ Vb = V + (size_t)b * LK_ * DV_ + t;
  float a0 = 0.f, a1 = 0.f;
  int j = 0;
  const int jv = vl & ~7;
  for (; j < jv; j += 8) {
    float v[8];
#pragma unroll
    for (int u = 0; u < 8; ++u) v[u] = Vb[(size_t)(j + u) * DV_];
#pragma unroll
    for (int u = 0; u < 8; ++u) {
      const float2 pp = p2s[j + u];
      a0 = fmaf(pp.x, v[u], a0);
      a1 = fmaf(pp.y, v[u], a1);
    }
  }
  for (; j < vl; ++j) {
    const float v = Vb[(size_t)j * DV_];
    const float2 pp = p2s[j];
    a0 = fmaf(pp.x, v, a0);
    a1 = fmaf(pp.y, v, a1);
  }
  out[(size_t)(b * LQ_ + i0) * DV_ + t]     = a0;
  out[(size_t)(b * LQ_ + i0 + 1) * DV_ + t] = a1;
}

extern "C" void kernel_launch(void* const* d_in, const int* in_sizes, int n_in,
                              void* d_out, int out_size, void* d_ws, size_t ws_size,
                              hipStream_t stream) {
  const float* queries    = (const float*)d_in[0];
  const float* keys       = (const float*)d_in[1];
  const float* values     = (const float*)d_in[2];
  const int*   valid_lens = (const int*)d_in[3];
  const float* Wq         = (const float*)d_in[4];
  const float* Wk         = (const float*)d_in[5];
  const float* wv         = (const float*)d_in[6];
  float* out = (float*)d_out;

  char* ws = (char*)d_ws;
  float* qpart   = (float*)ws;                           // 4 x 1 MB @ 0
  float* ekTpart = (float*)(ws + (size_t)( 4 << 20));    // 8 x 2 MB @ 4 MB
  float* ek2     = (float*)(ws + (size_t)(20 << 20));    // 2 MB     @ 20 MB

  proj_partial_kernel<<<1280, 256, 0, stream>>>(
      queries, keys, Wq, Wk, valid_lens, qpart, ekTpart);
  combine_ek_kernel<<<256, 512, 0, stream>>>(ekTpart, ek2);
  fused_attn_kernel<<<512, 512, 0, stream>>>(
      qpart, ek2, wv, valid_lens, values, out);
}

// Round 17
// 51.982 us; speedup vs baseline: 1.0378x; 1.0378x over previous
//
#include <hip/hip_runtime.h>

#define B_   4
#define LQ_  256
#define LK_  512
#define DIN_ 512
#define H_   256
#define DV_  512

#define L2E 1.4426950408889634f   // log2(e)
// tanh(x) = 1 - 2/(e^{2x}+1);  e^{2(q+k)} = e^{2q} * e^{2k}.
// eq2 = 2^clamp(2q*L2E,±126), ek2 likewise: each finite & nonzero.
// product inf -> rcp 0 (tanh=+1 exact); product 0 -> rcp 1 (tanh=-1 exact).
// Softmax WITHOUT max-subtract: |score| <= |Wsum|+2*sum|wv| ~ 38,
// e^38 ~ 3e16, sum <= 512*e^38 << fp32 max -> safe, exact masking via e=0.

// =====================================================================
// Kernel 1: proj PARTIAL GEMM (r15 structure — best measured).
// 64r x 128h tiles, 256 thr, micro 8r x 4h. d-split: Q=4, K=8.
// grid 640; dead K tiles exit.
//  Q out: qpart[ds4][(b,i)][h]   row-major
//  K out: ekTpart[ds8][b][h][j]  transposed
// =====================================================================
__global__ __launch_bounds__(256) void proj_partial_kernel(
    const float* __restrict__ Q, const float* __restrict__ K,
    const float* __restrict__ Wq, const float* __restrict__ Wk,
    const int* __restrict__ valid_lens,
    float* __restrict__ qpart, float* __restrict__ ekTpart) {
  __shared__ float xs[64][68];
  __shared__ float ws[64][132];

  const int blk = blockIdx.x;
  const bool isQ = blk < 128;
  int b, row0, h0, ds;
  if (isQ) {
    ds = blk & 3; h0 = ((blk >> 2) & 1) * 128;
    const int rt = blk >> 3;
    b = rt >> 2; row0 = (rt & 3) * 64;
  } else {
    const int u = blk - 128;
    ds = u & 7; h0 = ((u >> 3) & 1) * 128;
    const int rt = u >> 4;             // batch-interleaved
    b = rt & 3; row0 = (rt >> 2) * 64;
    if (row0 >= valid_lens[b]) return;
  }
  const int L = isQ ? LQ_ : LK_;
  const int dspan = isQ ? 128 : 64;
  const float* __restrict__ X  = (isQ ? Q : K) + ((size_t)(b * L + row0)) * DIN_ + ds * dspan;
  const float* __restrict__ Wb = (isQ ? Wq : Wk) + (size_t)(ds * dspan) * H_ + h0;

  const int t = threadIdx.x;
  const int hthr = t & 31;
  const int rthr = t >> 5;

  float acc[8][4];
#pragma unroll
  for (int r = 0; r < 8; ++r)
#pragma unroll
    for (int c = 0; c < 4; ++c) acc[r][c] = 0.f;

  for (int dd = 0; dd < dspan; dd += 64) {
    __syncthreads();
#pragma unroll
    for (int u = 0; u < 4; ++u) {
      const int f = t + 256 * u;
      const int r = f >> 4, c4 = (f & 15) << 2;
      *(float4*)&xs[r][c4] = *(const float4*)&X[(size_t)r * DIN_ + dd + c4];
    }
#pragma unroll
    for (int u = 0; u < 8; ++u) {
      const int f = t + 256 * u;
      const int k = f >> 5, c4 = (f & 31) << 2;
      *(float4*)&ws[k][c4] = *(const float4*)&Wb[(size_t)(dd + k) * H_ + c4];
    }
    __syncthreads();

    for (int k = 0; k < 64; k += 8) {
      float4 w4[8];
#pragma unroll
      for (int k8 = 0; k8 < 8; ++k8)
        w4[k8] = *(const float4*)&ws[k + k8][4 * hthr];
#pragma unroll
      for (int rr = 0; rr < 8; ++rr) {
        const float4 xa = *(const float4*)&xs[rthr * 8 + rr][k];
        const float4 xb = *(const float4*)&xs[rthr * 8 + rr][k + 4];
        const float xv[8] = {xa.x, xa.y, xa.z, xa.w, xb.x, xb.y, xb.z, xb.w};
#pragma unroll
        for (int k8 = 0; k8 < 8; ++k8) {
          acc[rr][0] = fmaf(xv[k8], w4[k8].x, acc[rr][0]);
          acc[rr][1] = fmaf(xv[k8], w4[k8].y, acc[rr][1]);
          acc[rr][2] = fmaf(xv[k8], w4[k8].z, acc[rr][2]);
          acc[rr][3] = fmaf(xv[k8], w4[k8].w, acc[rr][3]);
        }
      }
    }
  }

  if (isQ) {
    float* dst = qpart + (size_t)ds * (B_ * LQ_ * H_);
#pragma unroll
    for (int rr = 0; rr < 8; ++rr) {
      const int row = row0 + rthr * 8 + rr;
      float4 o = {acc[rr][0], acc[rr][1], acc[rr][2], acc[rr][3]};
      *(float4*)&dst[(size_t)(b * LQ_ + row) * H_ + h0 + 4 * hthr] = o;
    }
  } else {
    float* dst = ekTpart + (size_t)ds * (B_ * H_ * LK_);
#pragma unroll
    for (int c = 0; c < 4; ++c) {
      const int h = h0 + 4 * hthr + c;
      float* p = &dst[((size_t)b * H_ + h) * LK_ + row0 + rthr * 8];
      float4 lo = {acc[0][c], acc[1][c], acc[2][c], acc[3][c]};
      float4 hi = {acc[4][c], acc[5][c], acc[6][c], acc[7][c]};
      *(float4*)p = lo;
      *(float4*)(p + 4) = hi;
    }
  }
}

// =====================================================================
// Kernel 2: combine 8 ekT partials + SQUARED exp: ek2 = 2^clamp(2k*L2E,±126)
// =====================================================================
__global__ __launch_bounds__(512) void combine_ek_kernel(
    const float* __restrict__ ekTpart, float* __restrict__ ek2) {
  const int k4 = blockIdx.x * 512 + threadIdx.x;
  const size_t KN4 = (size_t)B_ * H_ * LK_ / 4;
  const float4* src = (const float4*)ekTpart;
  float4 s = src[k4];
#pragma unroll
  for (int p = 1; p < 8; ++p) {
    const float4 v = src[p * KN4 + k4];
    s.x += v.x; s.y += v.y; s.z += v.z; s.w += v.w;
  }
  float4 o;
  o.x = exp2f(fminf(fmaxf(s.x * (2.f * L2E), -126.f), 126.f));
  o.y = exp2f(fminf(fmaxf(s.y * (2.f * L2E), -126.f), 126.f));
  o.z = exp2f(fminf(fmaxf(s.z * (2.f * L2E), -126.f), 126.f));
  o.w = exp2f(fminf(fmaxf(s.w * (2.f * L2E), -126.f), 126.f));
  ((float4*)ek2)[k4] = o;
}

// =====================================================================
// Kernel 3: FUSED eq-combine + scores + softmax (no max-subtract) + AV.
// block = (b, 2 q-rows), 512 thr, grid 512 (2/CU), batch-pair swizzle.
// Phase 1 is vl-ADAPTIVE (block-uniform branch):
//   vl > 256: thread = j, full 256-h loop (waves past vl skip).
//   vl <= 256: thread = (j = t&255, h-half = t>>8) -> ALL 8 waves busy;
//              partials summed via ph[2][2][260] LDS.
// Inner: fmaf(q2,k2,1) -> rcp -> fmaf  (2 VALU + 1 trans / element).
// =====================================================================
__global__ __launch_bounds__(512) void fused_attn_kernel(
    const float* __restrict__ qpart, const float* __restrict__ ek2,
    const float* __restrict__ wv, const int* __restrict__ valid_lens,
    const float* __restrict__ V, float* __restrict__ out) {
  __shared__ float eqs[2][260];
  __shared__ float wvs[256];
  __shared__ float ph[2][2][260];
  __shared__ float2 p2s[LK_];
  __shared__ float reds[8][2];
  __shared__ float wsum_s;

  const int blk = blockIdx.x;
  const int b  = (blk & 3) ^ ((blk >> 8) & 1);
  const int i0 = (blk >> 2) * 2;
  const int vl = valid_lens[b];
  const int t = threadIdx.x;
  const int lane = t & 63, wave = t >> 6;

  // ---- phase 0: eq2 rows (squared exp), wv stage, wsum ----
  const size_t QN = (size_t)B_ * LQ_ * H_;
  {
    const int i = t >> 8, h = t & 255;
    const size_t base = (size_t)(b * LQ_ + i0 + i) * H_ + h;
    const float v = qpart[base] + qpart[QN + base] +
                    qpart[2 * QN + base] + qpart[3 * QN + base];
    eqs[i][h] = exp2f(fminf(fmaxf(v * (2.f * L2E), -126.f), 126.f));
  }
  if (t < 256) wvs[t] = wv[t];
  if (t < 64) {
    float s = wv[t] + wv[t + 64] + wv[t + 128] + wv[t + 192];
#pragma unroll
    for (int off = 32; off; off >>= 1) s += __shfl_xor(s, off);
    if (t == 0) wsum_s = s;
  }
  __syncthreads();
  const float Wsum = wsum_s;

  // ---- phase 1: scores (vl-adaptive) ----
  const bool valid = t < vl;
  float s[2] = {-3.0e38f, -3.0e38f};
  if (vl > 256) {
    if (valid) {
      const float* __restrict__ kb = ek2 + (size_t)b * H_ * LK_ + t;
      float a0 = 0.f, a1 = 0.f;
      for (int h = 0; h < H_; h += 16) {
        float kv[16];
#pragma unroll
        for (int u = 0; u < 16; ++u)
          kv[u] = kb[(size_t)(h + u) * LK_];        // 16 coalesced loads in flight
#pragma unroll
        for (int g = 0; g < 4; ++g) {
          const float4 w4  = *(const float4*)&wvs[h + 4 * g];
          const float4 q0v = *(const float4*)&eqs[0][h + 4 * g];
          const float4 q1v = *(const float4*)&eqs[1][h + 4 * g];
          const float ww[4] = {w4.x, w4.y, w4.z, w4.w};
          const float q0[4] = {q0v.x, q0v.y, q0v.z, q0v.w};
          const float q1[4] = {q1v.x, q1v.y, q1v.z, q1v.w};
#pragma unroll
          for (int u = 0; u < 4; ++u) {
            const float k2 = kv[4 * g + u];
            a0 = fmaf(ww[u], __builtin_amdgcn_rcpf(fmaf(q0[u], k2, 1.f)), a0);
            a1 = fmaf(ww[u], __builtin_amdgcn_rcpf(fmaf(q1[u], k2, 1.f)), a1);
          }
        }
      }
      s[0] = fmaf(-2.f, a0, Wsum);
      s[1] = fmaf(-2.f, a1, Wsum);
    }
  } else {
    // 256 j x 2 h-halves: all waves busy
    const int j = t & 255;
    const int hb = (t >> 8) * 128;
    if (j < vl) {
      const float* __restrict__ kb = ek2 + (size_t)b * H_ * LK_ + j;
      float a0 = 0.f, a1 = 0.f;
      for (int hh = 0; hh < 128; hh += 16) {
        const int h = hb + hh;
        float kv[16];
#pragma unroll
        for (int u = 0; u < 16; ++u)
          kv[u] = kb[(size_t)(h + u) * LK_];
#pragma unroll
        for (int g = 0; g < 4; ++g) {
          const float4 w4  = *(const float4*)&wvs[h + 4 * g];
          const float4 q0v = *(const float4*)&eqs[0][h + 4 * g];
          const float4 q1v = *(const float4*)&eqs[1][h + 4 * g];
          const float ww[4] = {w4.x, w4.y, w4.z, w4.w};
          const float q0[4] = {q0v.x, q0v.y, q0v.z, q0v.w};
          const float q1[4] = {q1v.x, q1v.y, q1v.z, q1v.w};
#pragma unroll
          for (int u = 0; u < 4; ++u) {
            const float k2 = kv[4 * g + u];
            a0 = fmaf(ww[u], __builtin_amdgcn_rcpf(fmaf(q0[u], k2, 1.f)), a0);
            a1 = fmaf(ww[u], __builtin_amdgcn_rcpf(fmaf(q1[u], k2, 1.f)), a1);
          }
        }
      }
      ph[t >> 8][0][j] = a0;
      ph[t >> 8][1][j] = a1;
    }
    __syncthreads();
    if (valid) {
      s[0] = fmaf(-2.f, ph[0][0][t] + ph[1][0][t], Wsum);
      s[1] = fmaf(-2.f, ph[0][1][t] + ph[1][1][t], Wsum);
    }
  }

  // ---- phase 2: softmax WITHOUT max-subtract ----
  float e[2], sum[2];
#pragma unroll
  for (int i = 0; i < 2; ++i) {
    e[i] = valid ? exp2f(s[i] * L2E) : 0.f;
    sum[i] = e[i];
  }
#pragma unroll
  for (int off = 32; off; off >>= 1)
#pragma unroll
    for (int i = 0; i < 2; ++i) sum[i] += __shfl_xor(sum[i], off);
  if (lane == 0)
#pragma unroll
    for (int i = 0; i < 2; ++i) reds[wave][i] = sum[i];
  __syncthreads();
  {
    float tot[2];
#pragma unroll
    for (int i = 0; i < 2; ++i) {
      tot[i] = reds[0][i];
#pragma unroll
      for (int w = 1; w < 8; ++w) tot[i] += reds[w][i];
    }
    float2 pv;
    pv.x = e[0] * __builtin_amdgcn_rcpf(tot[0]);
    pv.y = e[1] * __builtin_amdgcn_rcpf(tot[1]);
    p2s[t] = pv;
  }
  __syncthreads();

  // ---- phase 3: AV (thread = v-column), x8-unrolled V loads ----
  const float* __restrict__ Vb = V + (size_t)b * LK_ * DV_ + t;
  float a0 = 0.f, a1 = 0.f;
  int j = 0;
  const int jv = vl & ~7;
  for (; j < jv; j += 8) {
    float v[8];
#pragma unroll
    for (int u = 0; u < 8; ++u) v[u] = Vb[(size_t)(j + u) * DV_];
#pragma unroll
    for (int u = 0; u < 8; ++u) {
      const float2 pp = p2s[j + u];
      a0 = fmaf(pp.x, v[u], a0);
      a1 = fmaf(pp.y, v[u], a1);
    }
  }
  for (; j < vl; ++j) {
    const float v = Vb[(size_t)j * DV_];
    const float2 pp = p2s[j];
    a0 = fmaf(pp.x, v, a0);
    a1 = fmaf(pp.y, v, a1);
  }
  out[(size_t)(b * LQ_ + i0) * DV_ + t]     = a0;
  out[(size_t)(b * LQ_ + i0 + 1) * DV_ + t] = a1;
}

extern "C" void kernel_launch(void* const* d_in, const int* in_sizes, int n_in,
                              void* d_out, int out_size, void* d_ws, size_t ws_size,
                              hipStream_t stream) {
  const float* queries    = (const float*)d_in[0];
  const float* keys       = (const float*)d_in[1];
  const float* values     = (const float*)d_in[2];
  const int*   valid_lens = (const int*)d_in[3];
  const float* Wq         = (const float*)d_in[4];
  const float* Wk         = (const float*)d_in[5];
  const float* wv         = (const float*)d_in[6];
  float* out = (float*)d_out;

  char* ws = (char*)d_ws;
  float* qpart   = (float*)ws;                           // 4 x 1 MB @ 0
  float* ekTpart = (float*)(ws + (size_t)( 4 << 20));    // 8 x 2 MB @ 4 MB
  float* ek2     = (float*)(ws + (size_t)(20 << 20));    // 2 MB     @ 20 MB

  proj_partial_kernel<<<640, 256, 0, stream>>>(
      queries, keys, Wq, Wk, valid_lens, qpart, ekTpart);
  combine_ek_kernel<<<256, 512, 0, stream>>>(ekTpart, ek2);
  fused_attn_kernel<<<512, 512, 0, stream>>>(
      qpart, ek2, wv, valid_lens, values, out);
}